// Round 4
// baseline (254.817 us; speedup 1.0000x reference)
//
#include <hip/hip_runtime.h>
#include <math.h>

// CSR segmented softmax, round 4: no ebuf — atomic LDS sum + shfl gather.
//   - one wave owns 64 consecutive nodes (contiguous edge range, <= CAP)
//   - nbuf[j] = relative node id of edge j (byte), ragged word-packed writes
//   - e computed in REGISTERS (strided layout, coalesced dwordx4 global)
//   - per-node sum: ds_add_f32 of register e into ssum[id] (in-lane run
//     combining: ~82% of 4-edge groups -> 1 atomic)
//   - 1/sum fetched via __shfl(rinv, id) (node id == lane id, bpermute)
//   - ALL LDS traffic intra-wave -> no __syncthreads, only lgkmcnt fences
//   - LDS 2.37 KB/wave -> 32 waves/CU (vs round-3's 11)
#define NPW 64
#define WPB 4
#define BLOCK (64 * WPB)
#define NPB (NPW * WPB)
#define CAP 2048
#define MAXG 8                      // 4-edge groups per lane

// nbuf swizzle: +4 bytes per 128 breaks the stride-16B ragged-write conflict;
// reads at j0 = 4*lane + 256g stay word-aligned, contiguous, conflict-free.
__device__ __forceinline__ int nidx(int j) { return j + ((j >> 7) << 2); }
#define NBUF_BYTES (CAP + ((CAP >> 7) << 2))   // 2112

struct __align__(16) WaveLds {
  unsigned char nbuf[NBUF_BYTES];
  float         ssum[NPW];
};

__device__ __forceinline__ void lds_fence() {
  __asm__ volatile("s_waitcnt lgkmcnt(0)" ::: "memory");
}

__global__ __launch_bounds__(BLOCK, 6)
void seg_softmax_kernel(const int* __restrict__ row_ptr,
                        const float* __restrict__ scores,
                        float* __restrict__ out, int n_nodes) {
  __shared__ WaveLds w[WPB];        // 9472 B/block -> 8 blocks/CU (wave-capped)
  const int tid = threadIdx.x, wv = tid >> 6, lane = tid & 63;
  WaveLds& L = w[wv];
  const int base = blockIdx.x * NPB + wv * NPW;
  const int i0 = min(base + lane, n_nodes);
  const int i1 = min(base + lane + 1, n_nodes);
  const int ls = row_ptr[i0];
  const int le = row_ptr[i1];
  const int wstart = __shfl(ls, 0);
  const int wend   = __shfl(le, 63);
  const int range  = wend - wstart;
  if (range <= 0) return;           // wave-uniform; no barriers anywhere

  if (range <= CAP) {
    const int a = ls - wstart, b = le - wstart;

    // ---- phase A: global -> regs (coalesced dwordx4), uniform group guards
    float v[4 * MAXG];
    #pragma unroll
    for (int g = 0; g < MAXG; ++g) {
      if (256 * g < range) {                       // wave-uniform
        const int j0 = 4 * lane + 256 * g;
        if (j0 + 4 <= range) {
          const float4 q = *(const float4*)(scores + wstart + j0);
          v[4*g+0] = q.x; v[4*g+1] = q.y; v[4*g+2] = q.z; v[4*g+3] = q.w;
        } else {
          #pragma unroll
          for (int k = 0; k < 4; ++k)
            v[4*g+k] = (j0 + k < range) ? scores[wstart + j0 + k] : -INFINITY;
        }
      }
    }

    // ---- phase B: nbuf ragged writes + ssum init (overlaps load latency)
    L.ssum[lane] = 0.0f;
    {
      const unsigned wq = (unsigned)lane * 0x01010101u;
      int j = a;
      for (; (j & 3) && j < b; ++j) L.nbuf[nidx(j)] = (unsigned char)lane;
      for (; j + 4 <= b; j += 4) *(unsigned*)&L.nbuf[nidx(j)] = wq;
      for (; j < b; ++j) L.nbuf[nidx(j)] = (unsigned char)lane;
    }
    lds_fence();   // nbuf + ssum visible to this wave's cross-lane reads

    // ---- phase C: wave max (valid per-node shift constant), exp in regs
    float m = -INFINITY;
    #pragma unroll
    for (int g = 0; g < MAXG; ++g)
      if (256 * g < range) {
        #pragma unroll
        for (int k = 0; k < 4; ++k) m = fmaxf(m, v[4*g+k]);
      }
    #pragma unroll
    for (int off = 32; off; off >>= 1) m = fmaxf(m, __shfl_xor(m, off));
    #pragma unroll
    for (int g = 0; g < MAXG; ++g)
      if (256 * g < range) {
        #pragma unroll
        for (int k = 0; k < 4; ++k) v[4*g+k] = __expf(v[4*g+k] - m);
      }

    // ---- phase D: atomic per-node sums from register e
    unsigned ids[MAXG];
    #pragma unroll
    for (int g = 0; g < MAXG; ++g) {
      if (256 * g < range) {
        const int j0 = 4 * lane + 256 * g;
        const unsigned idw = *(const unsigned*)&L.nbuf[nidx(j0)];
        ids[g] = idw;
        if (j0 + 4 <= range) {
          if (idw == (idw & 255u) * 0x01010101u) {   // all 4 edges same node
            atomicAdd(&L.ssum[idw & 255u],
                      (v[4*g+0] + v[4*g+1]) + (v[4*g+2] + v[4*g+3]));
          } else {
            atomicAdd(&L.ssum[idw & 255u],          v[4*g+0]);
            atomicAdd(&L.ssum[(idw >> 8)  & 255u],  v[4*g+1]);
            atomicAdd(&L.ssum[(idw >> 16) & 255u],  v[4*g+2]);
            atomicAdd(&L.ssum[idw >> 24],           v[4*g+3]);
          }
        } else {
          #pragma unroll
          for (int k = 0; k < 4; ++k)
            if (j0 + k < range)
              atomicAdd(&L.ssum[(idw >> (8 * k)) & 255u], v[4*g+k]);
        }
      }
    }
    lds_fence();   // drain this wave's ds_adds (slices are wave-private)

    const float rinv = 1.0f / L.ssum[lane];   // empty node -> inf, never read

    // ---- phase E: out[j] = e * shfl(rinv, id), coalesced dwordx4 stores
    #pragma unroll
    for (int g = 0; g < MAXG; ++g) {
      if (256 * g < range) {
        const int j0 = 4 * lane + 256 * g;
        const unsigned idw = ids[g];
        float4 o;
        o.x = v[4*g+0] * __shfl(rinv, (int)(idw & 255u));
        o.y = v[4*g+1] * __shfl(rinv, (int)((idw >> 8)  & 255u));
        o.z = v[4*g+2] * __shfl(rinv, (int)((idw >> 16) & 255u));
        o.w = v[4*g+3] * __shfl(rinv, (int)(idw >> 24));
        if (j0 + 4 <= range) {
          *(float4*)(out + wstart + j0) = o;
        } else {
          #pragma unroll
          for (int k = 0; k < 4; ++k)
            if (j0 + k < range) out[wstart + j0 + k] = (&o.x)[k];
        }
      }
    }
  } else {
    // fallback (range > CAP): direct-global per-node; never taken on this
    // data. No barriers -> safe in multi-wave blocks.
    float m = -INFINITY;
    for (int j = ls; j < le; ++j) m = fmaxf(m, scores[j]);
    float s = 0.0f;
    for (int j = ls; j < le; ++j) {
      const float e = __expf(scores[j] - m);
      s += e;
      out[j] = e;
    }
    const float r = 1.0f / s;
    for (int j = ls; j < le; ++j) out[j] *= r;
  }
}

extern "C" void kernel_launch(void* const* d_in, const int* in_sizes, int n_in,
                              void* d_out, int out_size, void* d_ws, size_t ws_size,
                              hipStream_t stream) {
  const int*   row_ptr = (const int*)d_in[0];
  const float* scores  = (const float*)d_in[1];
  float*       out     = (float*)d_out;
  const int n_nodes = in_sizes[0] - 1;
  const int blocks  = (n_nodes + NPB - 1) / NPB;
  seg_softmax_kernel<<<blocks, BLOCK, 0, stream>>>(row_ptr, scores, out, n_nodes);
}